// Round 1
// baseline (142.029 us; speedup 1.0000x reference)
//
#include <hip/hip_runtime.h>

// Problem: N=16384 rows, D=1024 fp32. loss = mean_r(1 - cos(pc[r], aug[r]))
// cos = (a.b) / (max(||a||,eps) * max(||b||,eps)), eps=1e-12.
// Memory-bound: 128 MiB read, scalar out.

#define N_ROWS 16384
#define DIM 1024
#define BLOCKS 1024
#define TPB 256
#define WAVES_PER_BLOCK (TPB / 64)
#define TOTAL_WAVES (BLOCKS * WAVES_PER_BLOCK)   // 4096 waves, 4 rows each

__global__ __launch_bounds__(TPB) void cos_rows_kernel(
    const float4* __restrict__ a, const float4* __restrict__ b,
    float* __restrict__ partial)
{
    const int wave = threadIdx.x >> 6;
    const int lane = threadIdx.x & 63;
    const int gwave = blockIdx.x * WAVES_PER_BLOCK + wave;

    float sum_cos = 0.0f;

    for (int r = gwave; r < N_ROWS; r += TOTAL_WAVES) {
        const float4* ap = a + (size_t)r * (DIM / 4);
        const float4* bp = b + (size_t)r * (DIM / 4);
        float ab = 0.0f, aa = 0.0f, bb = 0.0f;
        #pragma unroll
        for (int k = 0; k < 4; ++k) {
            float4 x = ap[lane + 64 * k];
            float4 y = bp[lane + 64 * k];
            ab += x.x * y.x + x.y * y.y + x.z * y.z + x.w * y.w;
            aa += x.x * x.x + x.y * x.y + x.z * x.z + x.w * x.w;
            bb += y.x * y.x + y.y * y.y + y.z * y.z + y.w * y.w;
        }
        // 64-lane butterfly reduction
        #pragma unroll
        for (int off = 32; off > 0; off >>= 1) {
            ab += __shfl_down(ab, off);
            aa += __shfl_down(aa, off);
            bb += __shfl_down(bb, off);
        }
        if (lane == 0) {
            float na = fmaxf(sqrtf(aa), 1e-12f);
            float nb = fmaxf(sqrtf(bb), 1e-12f);
            sum_cos += ab / (na * nb);
        }
    }

    __shared__ float s[WAVES_PER_BLOCK];
    if (lane == 0) s[wave] = sum_cos;
    __syncthreads();
    if (threadIdx.x == 0) {
        float t = 0.0f;
        #pragma unroll
        for (int i = 0; i < WAVES_PER_BLOCK; ++i) t += s[i];
        partial[blockIdx.x] = t;
    }
}

__global__ __launch_bounds__(TPB) void finalize_kernel(
    const float* __restrict__ partial, float* __restrict__ out)
{
    const int wave = threadIdx.x >> 6;
    const int lane = threadIdx.x & 63;
    float t = 0.0f;
    for (int i = threadIdx.x; i < BLOCKS; i += TPB) t += partial[i];
    #pragma unroll
    for (int off = 32; off > 0; off >>= 1) t += __shfl_down(t, off);
    __shared__ float s[WAVES_PER_BLOCK];
    if (lane == 0) s[wave] = t;
    __syncthreads();
    if (threadIdx.x == 0) {
        float tot = 0.0f;
        #pragma unroll
        for (int i = 0; i < WAVES_PER_BLOCK; ++i) tot += s[i];
        out[0] = 1.0f - tot / (float)N_ROWS;
    }
}

extern "C" void kernel_launch(void* const* d_in, const int* in_sizes, int n_in,
                              void* d_out, int out_size, void* d_ws, size_t ws_size,
                              hipStream_t stream) {
    const float4* pc  = (const float4*)d_in[0];
    const float4* aug = (const float4*)d_in[1];
    float* partial = (float*)d_ws;       // BLOCKS floats = 4 KiB scratch
    float* out = (float*)d_out;

    cos_rows_kernel<<<BLOCKS, TPB, 0, stream>>>(pc, aug, partial);
    finalize_kernel<<<1, TPB, 0, stream>>>(partial, out);
}

// Round 2
// 141.137 us; speedup vs baseline: 1.0063x; 1.0063x over previous
//
#include <hip/hip_runtime.h>

// N=16384 rows, D=1024 fp32. loss = mean_r(1 - cos(pc[r], aug[r]))
// Memory-bound: 128 MiB read. R1 showed 42us @ 3.2 TB/s effective -> MLP-bound
// (loop-carried load->reduce->load serialization). Fix: one row per wave,
// no loop; 16384 waves, loads all issued before any consumption.

#define N_ROWS 16384
#define DIM_V4 256              // 1024 floats = 256 float4
#define TPB 256
#define WAVES_PER_BLOCK (TPB / 64)
#define BLOCKS (N_ROWS / WAVES_PER_BLOCK)   // 4096 blocks, 1 row per wave

__global__ __launch_bounds__(TPB) void cos_rows_kernel(
    const float4* __restrict__ a, const float4* __restrict__ b,
    float* __restrict__ partial)
{
    const int wave = threadIdx.x >> 6;
    const int lane = threadIdx.x & 63;
    const int r = blockIdx.x * WAVES_PER_BLOCK + wave;   // one row per wave

    const float4* ap = a + (size_t)r * DIM_V4;
    const float4* bp = b + (size_t)r * DIM_V4;

    // Issue all 8 16B loads back-to-back before any consumption.
    float4 x[4], y[4];
    #pragma unroll
    for (int k = 0; k < 4; ++k) x[k] = ap[lane + 64 * k];
    #pragma unroll
    for (int k = 0; k < 4; ++k) y[k] = bp[lane + 64 * k];

    float ab = 0.0f, aa = 0.0f, bb = 0.0f;
    #pragma unroll
    for (int k = 0; k < 4; ++k) {
        ab += x[k].x * y[k].x + x[k].y * y[k].y + x[k].z * y[k].z + x[k].w * y[k].w;
        aa += x[k].x * x[k].x + x[k].y * x[k].y + x[k].z * x[k].z + x[k].w * x[k].w;
        bb += y[k].x * y[k].x + y[k].y * y[k].y + y[k].z * y[k].z + y[k].w * y[k].w;
    }

    // 64-lane butterfly reduction (3 independent chains -> good ILP)
    #pragma unroll
    for (int off = 32; off > 0; off >>= 1) {
        ab += __shfl_down(ab, off);
        aa += __shfl_down(aa, off);
        bb += __shfl_down(bb, off);
    }

    __shared__ float s[WAVES_PER_BLOCK];
    if (lane == 0) {
        float na = fmaxf(sqrtf(aa), 1e-12f);
        float nb = fmaxf(sqrtf(bb), 1e-12f);
        s[wave] = ab / (na * nb);
    }
    __syncthreads();
    if (threadIdx.x == 0) {
        float t = 0.0f;
        #pragma unroll
        for (int i = 0; i < WAVES_PER_BLOCK; ++i) t += s[i];
        partial[blockIdx.x] = t;
    }
}

__global__ __launch_bounds__(1024) void finalize_kernel(
    const float* __restrict__ partial, float* __restrict__ out)
{
    const int wave = threadIdx.x >> 6;
    const int lane = threadIdx.x & 63;
    float t = 0.0f;
    #pragma unroll
    for (int i = 0; i < BLOCKS / 1024; ++i) t += partial[threadIdx.x + 1024 * i];
    #pragma unroll
    for (int off = 32; off > 0; off >>= 1) t += __shfl_down(t, off);
    __shared__ float s[1024 / 64];
    if (lane == 0) s[wave] = t;
    __syncthreads();
    if (threadIdx.x == 0) {
        float tot = 0.0f;
        #pragma unroll
        for (int i = 0; i < 1024 / 64; ++i) tot += s[i];
        out[0] = 1.0f - tot / (float)N_ROWS;
    }
}

extern "C" void kernel_launch(void* const* d_in, const int* in_sizes, int n_in,
                              void* d_out, int out_size, void* d_ws, size_t ws_size,
                              hipStream_t stream) {
    const float4* pc  = (const float4*)d_in[0];
    const float4* aug = (const float4*)d_in[1];
    float* partial = (float*)d_ws;       // BLOCKS floats = 16 KiB scratch
    float* out = (float*)d_out;

    cos_rows_kernel<<<BLOCKS, TPB, 0, stream>>>(pc, aug, partial);
    finalize_kernel<<<1, 1024, 0, stream>>>(partial, out);
}